// Round 1
// baseline (2367.845 us; speedup 1.0000x reference)
//
#include <hip/hip_runtime.h>
#include <math.h>

// Problem constants: V=32000 D=512 H=512 L=2 B=64 S=64 -> T=Te=63
#define NEGV -1000000000.0f

typedef unsigned short u16;
typedef __attribute__((ext_vector_type(8))) short bf16x8;
typedef __attribute__((ext_vector_type(4))) float f32x4;

__device__ __forceinline__ u16 f2bf(float f){
  union { float f; unsigned u; } v; v.f = f;
  unsigned u = v.u;
  unsigned r = (u + 0x7fffu + ((u >> 16) & 1u)) >> 16;
  return (u16)r;
}
__device__ __forceinline__ float bf2f(u16 b){
  union { unsigned u; float f; } v; v.u = ((unsigned)b) << 16;
  return v.f;
}
__device__ __forceinline__ float sigmf(float x){ return 1.f / (1.f + __expf(-x)); }
__device__ __forceinline__ float tanhf_(float x){
  float e = __expf(-2.f * fabsf(x));
  float t = (1.f - e) / (1.f + e);
  return x >= 0.f ? t : -t;
}
__device__ __forceinline__ float wred64(float v){
  #pragma unroll
  for (int m = 32; m; m >>= 1) v += __shfl_xor(v, m, 64);
  return v;
}
__device__ __forceinline__ float wmax64(float v){
  #pragma unroll
  for (int m = 32; m; m >>= 1) v = fmaxf(v, __shfl_xor(v, m, 64));
  return v;
}

// ---------------- prep: fp32 -> bf16 weight copies + bias sums ----------------
__global__ __launch_bounds__(256) void k_prep(
    const float* wih, const float* whh, const float* we, const float* wh,
    const float* fcw, const float* enc, const float* bih, const float* bhh,
    u16* wihb, u16* whhb, u16* web, u16* whb, u16* fcwb, u16* encb, float* b01)
{
  const long n0 = 2097152, n1 = 2097152, n2 = 262144, n3 = 262144;
  const long n4 = 32768000, n5 = 2064384, n6 = 4096;
  const long total = n0 + n1 + n2 + n3 + n4 + n5 + n6;
  long stride = (long)gridDim.x * 256;
  for (long i = (long)blockIdx.x * 256 + threadIdx.x; i < total; i += stride){
    long j = i;
    if (j < n0){ wihb[j] = f2bf(wih[j]); continue; } j -= n0;
    if (j < n1){ whhb[j] = f2bf(whh[j]); continue; } j -= n1;
    if (j < n2){ web[j]  = f2bf(we[j]);  continue; } j -= n2;
    if (j < n3){ whb[j]  = f2bf(wh[j]);  continue; } j -= n3;
    if (j < n4){ fcwb[j] = f2bf(fcw[j]); continue; } j -= n4;
    if (j < n5){ encb[j] = f2bf(enc[j]); continue; } j -= n5;
    b01[j] = bih[j] + bhh[j];   // j<2048: layer0 bias sum; 2048..4095: layer1
  }
}

// ---------------- embedding gather -> bf16 ----------------
__global__ __launch_bounds__(256) void k_embed(const int* X, const float* emb, u16* ebf){
  int row = blockIdx.x;            // t*64 + b
  int t = row >> 6, b = row & 63;
  int tok = X[b * 64 + t];         // X is (B=64, S=64)
  const float* src = emb + (long)tok * 512;
  u16* dst = ebf + (long)row * 512;
  for (int j = threadIdx.x; j < 512; j += 256) dst[j] = f2bf(src[j]);
}

// ---------------- generic bf16 GEMM: C(M,N) = A(M,K) @ B(N,K)^T + bias ----------------
// grid (Mtiles, Ntiles), BM=BN=64, BK=32. M,N mult of 64, K mult of 32.
__global__ __launch_bounds__(256) void gemm_bt(
    const u16* Am, int lda, const u16* Bm, int ldb,
    float* C, int ldc, const float* bias, int K)
{
  __shared__ u16 sA[64 * 32], sB[64 * 32];
  int tm = blockIdx.x, tn = blockIdx.y;
  int tid = threadIdx.x;
  int wave = tid >> 6, lane = tid & 63;
  int wm = wave >> 1, wn = wave & 1;
  int q = lane >> 4, cl = lane & 15;
  f32x4 acc[2][2];
  #pragma unroll
  for (int i = 0; i < 2; i++)
    #pragma unroll
    for (int j = 0; j < 2; j++) acc[i][j] = (f32x4){0.f, 0.f, 0.f, 0.f};

  int r = tid >> 2, ck = tid & 3;
  const u16* Ags = Am + (long)(tm * 64 + r) * lda + ck * 8;
  const u16* Bgs = Bm + (long)(tn * 64 + r) * ldb + ck * 8;
  u16* sAw = &sA[r * 32 + ck * 8];
  u16* sBw = &sB[r * 32 + ck * 8];

  for (int kt = 0; kt < K; kt += 32){
    *(uint4*)sAw = *(const uint4*)(Ags + kt);
    *(uint4*)sBw = *(const uint4*)(Bgs + kt);
    __syncthreads();
    #pragma unroll
    for (int i = 0; i < 2; i++){
      bf16x8 af = *(const bf16x8*)&sA[(wm * 32 + i * 16 + cl) * 32 + q * 8];
      #pragma unroll
      for (int j = 0; j < 2; j++){
        bf16x8 bfv = *(const bf16x8*)&sB[(wn * 32 + j * 16 + cl) * 32 + q * 8];
        acc[i][j] = __builtin_amdgcn_mfma_f32_16x16x32_bf16(af, bfv, acc[i][j], 0, 0, 0);
      }
    }
    __syncthreads();
  }
  #pragma unroll
  for (int i = 0; i < 2; i++)
    #pragma unroll
    for (int j = 0; j < 2; j++){
      int colg = tn * 64 + wn * 32 + j * 16 + cl;
      float bv = bias ? bias[colg] : 0.f;
      #pragma unroll
      for (int rr = 0; rr < 4; rr++){
        int rowg = tm * 64 + wm * 32 + i * 16 + q * 4 + rr;
        C[(long)rowg * ldc + colg] = acc[i][j][rr] + bv;
      }
    }
}

// ---------------- LSTM tick: layer0(t=k) + layer1(t=k-1) pipelined ----------------
// blk 0..31: layer0 (16 cell-cols each); blk 32..63: layer1.
__global__ __launch_bounds__(256) void lstm_tick(int k,
    const u16* h0p, u16* h0n, const u16* h1p, u16* h1n,
    float* c0, float* c1, const float* x0,
    const u16* whh0, const u16* wih1, const u16* whh1,
    const float* b1s, u16* feat)
{
  int blk = blockIdx.x;
  int layer = blk >> 5;
  int t = layer ? (k - 1) : k;
  if (t < 0 || t > 62) return;
  int cc = (blk & 31) * 16;
  int wave = threadIdx.x >> 6, lane = threadIdx.x & 63;
  int q = lane >> 4, cl = lane & 15;
  f32x4 acc[4];
  #pragma unroll
  for (int g = 0; g < 4; g++) acc[g] = (f32x4){0.f, 0.f, 0.f, 0.f};

  const u16* Am = h0p;                      // layer1 pass0 also consumes h0(t=k-1)
  const u16* Bm = layer ? wih1 : whh0;
  #pragma unroll 1
  for (int pass = 0; pass < 1 + layer; pass++){
    if (pass == 1){ Am = h1p; Bm = whh1; }
    const u16* Ab = Am + (wave * 16 + cl) * 512 + q * 8;
    #pragma unroll 4
    for (int kt = 0; kt < 16; kt++){
      bf16x8 af = *(const bf16x8*)(Ab + kt * 32);
      #pragma unroll
      for (int g = 0; g < 4; g++){
        const u16* Bp = Bm + (long)(g * 512 + cc + cl) * 512 + kt * 32 + q * 8;
        bf16x8 bfv = *(const bf16x8*)Bp;
        acc[g] = __builtin_amdgcn_mfma_f32_16x16x32_bf16(af, bfv, acc[g], 0, 0, 0);
      }
    }
  }
  float* cb = layer ? c1 : c0;
  u16* hn = layer ? h1n : h0n;
  #pragma unroll
  for (int rr = 0; rr < 4; rr++){
    int s = wave * 16 + q * 4 + rr;
    int j = cc + cl;
    float gi, gf, gg, go;
    if (layer == 0){
      const float* xr = x0 + (long)(t * 64 + s) * 2048 + j;
      gi = acc[0][rr] + xr[0];    gf = acc[1][rr] + xr[512];
      gg = acc[2][rr] + xr[1024]; go = acc[3][rr] + xr[1536];
    } else {
      gi = acc[0][rr] + b1s[j];        gf = acc[1][rr] + b1s[512 + j];
      gg = acc[2][rr] + b1s[1024 + j]; go = acc[3][rr] + b1s[1536 + j];
    }
    float cold = cb[s * 512 + j];
    float cn = sigmf(gf) * cold + sigmf(gi) * tanhf_(gg);
    cb[s * 512 + j] = cn;
    float hv = sigmf(go) * tanhf_(cn);
    u16 hb = f2bf(hv);
    hn[s * 512 + j] = hb;
    if (layer) feat[(long)(t * 64 + s) * 1024 + j] = hb;   // top_t
  }
}

// ---------------- attention scores: s[t,b,e] = sum_h vw[h]*tanh(q[t,b,h]+encp[b,e,h]) ----------------
__global__ __launch_bounds__(256) void k_scores(
    const float* qb, const float* encp, const float* vw, float* scores)
{
  int row = blockIdx.x;       // t*64 + b
  int b = row & 63;
  int wave = threadIdx.x >> 6, lane = threadIdx.x & 63;
  float qv[8], vwv[8];
  const float* qr = qb + (long)row * 512 + lane * 8;
  #pragma unroll
  for (int i = 0; i < 8; i++){ qv[i] = qr[i]; vwv[i] = vw[lane * 8 + i]; }
  for (int e = wave; e < 63; e += 4){
    const float* er = encp + (long)(b * 63 + e) * 512 + lane * 8;
    float s = 0.f;
    #pragma unroll
    for (int i = 0; i < 8; i++) s += vwv[i] * tanhf_(qv[i] + er[i]);
    s = wred64(s);
    if (lane == 0) scores[(long)row * 63 + e] = s;
  }
}

// ---------------- softmax over BATCH axis (reference quirk), in-place ----------------
__global__ __launch_bounds__(64) void k_att(float* scores, const unsigned char* mask){
  int idx = blockIdx.x;            // t*63 + e
  int t = idx / 63, e = idx - t * 63;
  int lane = threadIdx.x;          // = b
  long off = (long)(t * 64 + lane) * 63 + e;
  float s = scores[off];
  if (mask[((t + 62) % 63) * 63 + e]) s = NEGV;   // (t-1) mod 63
  float M = wmax64(s);
  float p = __expf(s - M);
  float S = wred64(p);
  scores[off] = p / S;
}

// ---------------- weighted[t,b,h] = sum_e att[t,b,e]*enc[b,e,h] -> feat[:,512:1024] ----------------
__global__ __launch_bounds__(256) void k_weighted(
    const float* att, const float* enc, u16* feat)
{
  int row = blockIdx.x;   // t*64 + b
  int b = row & 63;
  int j = threadIdx.x;
  float a0 = 0.f, a1 = 0.f;
  const float* ar = att + (long)row * 63;
  const float* er = enc + (long)b * 63 * 512;
  for (int e = 0; e < 63; e++){
    float a = ar[e];
    a0 += a * er[(long)e * 512 + j];
    a1 += a * er[(long)e * 512 + j + 256];
  }
  feat[(long)row * 1024 + 512 + j] = f2bf(a0);
  feat[(long)row * 1024 + 768 + j] = f2bf(a1);
}

// ---------------- fc GEMM 128x128 tiles + logsumexp-partial epilogue ----------------
// A = feat (4096,1024) bf16, B = fc_W (32000,1024) bf16. grid (32, 250).
__global__ __launch_bounds__(256) void gemm_fc(
    const u16* Am, const u16* Bm, const float* fcb, float* partials)
{
  __shared__ u16 sA[128 * 32], sB[128 * 32];
  __shared__ float sm[128][2], ss[128][2];
  int tm = blockIdx.x, tn = blockIdx.y;
  int tid = threadIdx.x;
  int wave = tid >> 6, lane = tid & 63;
  int wm = wave >> 1, wn = wave & 1;
  int q = lane >> 4, cl = lane & 15;
  f32x4 acc[4][4];
  #pragma unroll
  for (int i = 0; i < 4; i++)
    #pragma unroll
    for (int j = 0; j < 4; j++) acc[i][j] = (f32x4){0.f, 0.f, 0.f, 0.f};

  const u16 *Ag[2], *Bg[2];
  u16 *sAw[2], *sBw[2];
  #pragma unroll
  for (int h = 0; h < 2; h++){
    int idx = h * 256 + tid, rr = idx >> 2, ck = idx & 3;
    Ag[h] = Am + (long)(tm * 128 + rr) * 1024 + ck * 8;
    Bg[h] = Bm + (long)(tn * 128 + rr) * 1024 + ck * 8;
    sAw[h] = &sA[rr * 32 + ck * 8];
    sBw[h] = &sB[rr * 32 + ck * 8];
  }
  for (int kt = 0; kt < 1024; kt += 32){
    #pragma unroll
    for (int h = 0; h < 2; h++){
      *(uint4*)sAw[h] = *(const uint4*)(Ag[h] + kt);
      *(uint4*)sBw[h] = *(const uint4*)(Bg[h] + kt);
    }
    __syncthreads();
    bf16x8 afr[4];
    #pragma unroll
    for (int mt = 0; mt < 4; mt++)
      afr[mt] = *(const bf16x8*)&sA[(wm * 64 + mt * 16 + cl) * 32 + q * 8];
    #pragma unroll
    for (int nt = 0; nt < 4; nt++){
      bf16x8 bfv = *(const bf16x8*)&sB[(wn * 64 + nt * 16 + cl) * 32 + q * 8];
      #pragma unroll
      for (int mt = 0; mt < 4; mt++)
        acc[mt][nt] = __builtin_amdgcn_mfma_f32_16x16x32_bf16(afr[mt], bfv, acc[mt][nt], 0, 0, 0);
    }
    __syncthreads();
  }
  // per-row (max, sum-exp) over this WG's 128 cols
  float fb[4];
  #pragma unroll
  for (int nt = 0; nt < 4; nt++) fb[nt] = fcb[tn * 128 + wn * 64 + nt * 16 + cl];
  #pragma unroll
  for (int mt = 0; mt < 4; mt++){
    #pragma unroll
    for (int rr = 0; rr < 4; rr++){
      float vals[4];
      float vm = -3.0e38f, vs = 0.f;
      #pragma unroll
      for (int nt = 0; nt < 4; nt++){ float v = acc[mt][nt][rr] + fb[nt]; vals[nt] = v; vm = fmaxf(vm, v); }
      #pragma unroll
      for (int nt = 0; nt < 4; nt++) vs += __expf(vals[nt] - vm);
      #pragma unroll
      for (int m = 1; m < 16; m <<= 1){
        float om = __shfl_xor(vm, m, 16);
        float os = __shfl_xor(vs, m, 16);
        float nm = fmaxf(vm, om);
        vs = vs * __expf(vm - nm) + os * __expf(om - nm);
        vm = nm;
      }
      if (cl == 0){ int rl = wm * 64 + mt * 16 + q * 4 + rr; sm[rl][wn] = vm; ss[rl][wn] = vs; }
    }
  }
  __syncthreads();
  if (tid < 128){
    float m0 = sm[tid][0], m1 = sm[tid][1];
    float M = fmaxf(m0, m1);
    float S = ss[tid][0] * __expf(m0 - M) + ss[tid][1] * __expf(m1 - M);
    long row = tm * 128 + tid;
    partials[(row * 250 + tn) * 2]     = M;
    partials[(row * 250 + tn) * 2 + 1] = S;
  }
}

// ---------------- per-row logsumexp combine + target logit -> nll ----------------
__global__ __launch_bounds__(256) void k_rowstats(
    const float* partials, const u16* feat, const u16* fcwb,
    const float* fcb, const int* X, float* nll)
{
  int row = blockIdx.x * 4 + (threadIdx.x >> 6);
  int lane = threadIdx.x & 63;
  if (row >= 4032) return;
  float vm = -3.0e38f, vs = 0.f;
  const float* pr = partials + (long)row * 500;
  for (int i = lane; i < 250; i += 64){
    float m = pr[i * 2], s2 = pr[i * 2 + 1];
    float nm = fmaxf(vm, m);
    vs = vs * __expf(vm - nm) + s2 * __expf(m - nm);
    vm = nm;
  }
  #pragma unroll
  for (int m = 32; m; m >>= 1){
    float om = __shfl_xor(vm, m, 64);
    float os = __shfl_xor(vs, m, 64);
    float nm = fmaxf(vm, om);
    vs = vs * __expf(vm - nm) + os * __expf(om - nm);
    vm = nm;
  }
  float logZ = vm + __logf(vs);
  int t = row >> 6, b = row & 63;
  int tgt = X[b * 64 + t + 1];
  const u16* fr = feat + (long)row * 1024 + lane * 16;
  const u16* wr = fcwb + (long)tgt * 1024 + lane * 16;
  float d = 0.f;
  #pragma unroll
  for (int i = 0; i < 16; i++) d += bf2f(fr[i]) * bf2f(wr[i]);
  d = wred64(d);
  if (lane == 0) nll[row] = logZ - (d + fcb[tgt]);
}

// ---------------- final masked mean ----------------
__global__ __launch_bounds__(256) void k_final(const float* nll, const int* X, float* out){
  __shared__ float lt[64];
  int wave = threadIdx.x >> 6, lane = threadIdx.x & 63;
  for (int t = wave; t < 63; t += 4){
    int tgt = X[lane * 64 + t + 1];
    float v = (tgt != 0) ? nll[t * 64 + lane] : 0.f;
    float c = (tgt != 0) ? 1.f : 0.f;
    v = wred64(v); c = wred64(c);
    if (lane == 0) lt[t] = v / c;
  }
  __syncthreads();
  if (threadIdx.x == 0){
    float s = 0.f;
    for (int t = 0; t < 63; t++) s += lt[t];
    out[0] = s / 63.f;
  }
}

extern "C" void kernel_launch(void* const* d_in, const int* in_sizes, int n_in,
                              void* d_out, int out_size, void* d_ws, size_t ws_size,
                              hipStream_t stream)
{
  (void)in_sizes; (void)n_in; (void)out_size; (void)ws_size;
  const int*   X    = (const int*)d_in[0];
  const float* enc  = (const float*)d_in[1];
  const unsigned char* mask = (const unsigned char*)d_in[2];
  const float* emb  = (const float*)d_in[3];
  const float* wih  = (const float*)d_in[4];
  const float* whh  = (const float*)d_in[5];
  const float* bih  = (const float*)d_in[6];
  const float* bhh  = (const float*)d_in[7];
  const float* awh  = (const float*)d_in[8];
  const float* awe  = (const float*)d_in[9];
  const float* ab   = (const float*)d_in[10];
  const float* vw   = (const float*)d_in[11];
  const float* fcw  = (const float*)d_in[12];
  const float* fcb  = (const float*)d_in[13];
  float* out = (float*)d_out;

  char* w = (char*)d_ws;
  size_t o = 0;
  auto alloc = [&](size_t bytes){ size_t r = o; o = (o + bytes + 255) & ~(size_t)255; return r; };
  size_t o_ebf  = alloc((size_t)4032 * 512 * 2);
  size_t o_wihb = alloc((size_t)2 * 2048 * 512 * 2);
  size_t o_whhb = alloc((size_t)2 * 2048 * 512 * 2);
  size_t o_web  = alloc((size_t)512 * 512 * 2);
  size_t o_whb  = alloc((size_t)512 * 512 * 2);
  size_t o_fcwb = alloc((size_t)32000 * 1024 * 2);
  size_t o_encb = alloc((size_t)4032 * 512 * 2);
  size_t o_b01  = alloc((size_t)4096 * 4);
  size_t o_x0   = alloc((size_t)4032 * 2048 * 4);
  size_t o_encp = alloc((size_t)4032 * 512 * 4);
  size_t o_q    = alloc((size_t)4032 * 512 * 4);
  size_t o_feat = alloc((size_t)4096 * 1024 * 2);
  size_t o_hc   = alloc((size_t)(4 * 64 * 512 * 2 + 2 * 64 * 512 * 4));
  size_t o_sc   = alloc((size_t)63 * 64 * 63 * 4);
  size_t o_part = alloc((size_t)4096 * 250 * 2 * 4);
  size_t o_nll  = alloc((size_t)4032 * 4);

  u16* ebf   = (u16*)(w + o_ebf);
  u16* wihb  = (u16*)(w + o_wihb);
  u16* whhb  = (u16*)(w + o_whhb);
  u16* web   = (u16*)(w + o_web);
  u16* whb   = (u16*)(w + o_whb);
  u16* fcwb  = (u16*)(w + o_fcwb);
  u16* encb  = (u16*)(w + o_encb);
  float* b01 = (float*)(w + o_b01);
  float* x0  = (float*)(w + o_x0);
  float* encp= (float*)(w + o_encp);
  float* qb  = (float*)(w + o_q);
  u16* feat  = (u16*)(w + o_feat);
  u16* h0b   = (u16*)(w + o_hc);
  u16* h1b   = h0b + 2 * 64 * 512;
  float* c0  = (float*)(h1b + 2 * 64 * 512);
  float* c1  = c0 + 64 * 512;
  float* sc  = (float*)(w + o_sc);
  float* part= (float*)(w + o_part);
  float* nllb= (float*)(w + o_nll);

  // zero h0[2], h1[2], c0, c1 (one contiguous region)
  hipMemsetAsync(w + o_hc, 0, (size_t)(4 * 64 * 512 * 2 + 2 * 64 * 512 * 4), stream);

  k_prep<<<4096, 256, 0, stream>>>(wih, whh, awe, awh, fcw, enc, bih, bhh,
                                   wihb, whhb, web, whb, fcwb, encb, b01);
  k_embed<<<4032, 256, 0, stream>>>(X, emb, ebf);

  // X0 = E @ Wih0^T + (bih0+bhh0): (4032,2048) K=512
  gemm_bt<<<dim3(63, 32), 256, 0, stream>>>(ebf, 512, wihb, 512, x0, 2048, b01, 512);
  // enc_proj = enc @ We^T + attn_b: (4032,512) K=512 (rows b*63+e)
  gemm_bt<<<dim3(63, 8), 256, 0, stream>>>(encb, 512, web, 512, encp, 512, ab, 512);

  // sequential LSTM: 64 pipelined ticks
  for (int k = 0; k < 64; k++){
    const u16* h0p = h0b + ((k + 1) & 1) * (64 * 512);
    u16* h0n       = h0b + (k & 1) * (64 * 512);
    const u16* h1p = h1b + ((k + 1) & 1) * (64 * 512);
    u16* h1n       = h1b + (k & 1) * (64 * 512);
    lstm_tick<<<64, 256, 0, stream>>>(k, h0p, h0n, h1p, h1n, c0, c1, x0,
        whhb, wihb + 2048 * 512, whhb + 2048 * 512, b01 + 2048, feat);
  }

  // q = top @ Wh^T: A = feat[:, :512] (lda=1024)
  gemm_bt<<<dim3(63, 8), 256, 0, stream>>>(feat, 1024, whb, 512, qb, 512, nullptr, 512);
  k_scores<<<4032, 256, 0, stream>>>(qb, encp, vw, sc);
  k_att<<<3969, 64, 0, stream>>>(sc, mask);
  k_weighted<<<4032, 256, 0, stream>>>(sc, enc, feat);

  gemm_fc<<<dim3(32, 250), 256, 0, stream>>>(feat, fcwb, fcb, part);
  k_rowstats<<<1008, 256, 0, stream>>>(part, feat, fcwb, fcb, X, nllb);
  k_final<<<1, 256, 0, stream>>>(nllb, X, out);
}

// Round 2
// 2203.496 us; speedup vs baseline: 1.0746x; 1.0746x over previous
//
#include <hip/hip_runtime.h>
#include <math.h>

// Problem constants: V=32000 D=512 H=512 L=2 B=64 S=64 -> T=Te=63
#define NEGV -1000000000.0f

typedef unsigned short u16;
typedef __attribute__((ext_vector_type(8))) short bf16x8;
typedef __attribute__((ext_vector_type(4))) float f32x4;

__device__ __forceinline__ u16 f2bf(float f){
  union { float f; unsigned u; } v; v.f = f;
  unsigned u = v.u;
  unsigned r = (u + 0x7fffu + ((u >> 16) & 1u)) >> 16;
  return (u16)r;
}
__device__ __forceinline__ float bf2f(u16 b){
  union { unsigned u; float f; } v; v.u = ((unsigned)b) << 16;
  return v.f;
}
__device__ __forceinline__ float sigmf(float x){ return 1.f / (1.f + __expf(-x)); }
__device__ __forceinline__ float tanhf_(float x){
  float e = __expf(-2.f * fabsf(x));
  float t = (1.f - e) / (1.f + e);
  return x >= 0.f ? t : -t;
}
__device__ __forceinline__ float wred64(float v){
  #pragma unroll
  for (int m = 32; m; m >>= 1) v += __shfl_xor(v, m, 64);
  return v;
}
__device__ __forceinline__ float wmax64(float v){
  #pragma unroll
  for (int m = 32; m; m >>= 1) v = fmaxf(v, __shfl_xor(v, m, 64));
  return v;
}

// ---------------- prep: fp32 -> bf16 weight copies + bias sums ----------------
__global__ __launch_bounds__(256) void k_prep(
    const float* wih, const float* whh, const float* we, const float* wh,
    const float* fcw, const float* enc, const float* bih, const float* bhh,
    u16* wihb, u16* whhb, u16* web, u16* whb, u16* fcwb, u16* encb, float* b01)
{
  const long n0 = 2097152, n1 = 2097152, n2 = 262144, n3 = 262144;
  const long n4 = 32768000, n5 = 2064384, n6 = 4096;
  const long total = n0 + n1 + n2 + n3 + n4 + n5 + n6;
  long stride = (long)gridDim.x * 256;
  for (long i = (long)blockIdx.x * 256 + threadIdx.x; i < total; i += stride){
    long j = i;
    if (j < n0){ wihb[j] = f2bf(wih[j]); continue; } j -= n0;
    if (j < n1){ whhb[j] = f2bf(whh[j]); continue; } j -= n1;
    if (j < n2){ web[j]  = f2bf(we[j]);  continue; } j -= n2;
    if (j < n3){ whb[j]  = f2bf(wh[j]);  continue; } j -= n3;
    if (j < n4){ fcwb[j] = f2bf(fcw[j]); continue; } j -= n4;
    if (j < n5){ encb[j] = f2bf(enc[j]); continue; } j -= n5;
    b01[j] = bih[j] + bhh[j];   // j<2048: layer0 bias sum; 2048..4095: layer1
  }
}

// ---------------- embedding gather -> bf16 ----------------
__global__ __launch_bounds__(256) void k_embed(const int* X, const float* emb, u16* ebf){
  int row = blockIdx.x;            // t*64 + b
  int t = row >> 6, b = row & 63;
  int tok = X[b * 64 + t];         // X is (B=64, S=64)
  const float* src = emb + (long)tok * 512;
  u16* dst = ebf + (long)row * 512;
  for (int j = threadIdx.x; j < 512; j += 256) dst[j] = f2bf(src[j]);
}

// ---------------- generic bf16 GEMM: C(M,N) = A(M,K) @ B(N,K)^T + bias ----------------
// grid (Mtiles, Ntiles), BM=BN=64, BK=32. M,N mult of 64, K mult of 32.
__global__ __launch_bounds__(256) void gemm_bt(
    const u16* Am, int lda, const u16* Bm, int ldb,
    float* C, int ldc, const float* bias, int K)
{
  __shared__ u16 sA[64 * 32], sB[64 * 32];
  int tm = blockIdx.x, tn = blockIdx.y;
  int tid = threadIdx.x;
  int wave = tid >> 6, lane = tid & 63;
  int wm = wave >> 1, wn = wave & 1;
  int q = lane >> 4, cl = lane & 15;
  f32x4 acc[2][2];
  #pragma unroll
  for (int i = 0; i < 2; i++)
    #pragma unroll
    for (int j = 0; j < 2; j++) acc[i][j] = (f32x4){0.f, 0.f, 0.f, 0.f};

  int r = tid >> 2, ck = tid & 3;
  const u16* Ags = Am + (long)(tm * 64 + r) * lda + ck * 8;
  const u16* Bgs = Bm + (long)(tn * 64 + r) * ldb + ck * 8;
  u16* sAw = &sA[r * 32 + ck * 8];
  u16* sBw = &sB[r * 32 + ck * 8];

  for (int kt = 0; kt < K; kt += 32){
    *(uint4*)sAw = *(const uint4*)(Ags + kt);
    *(uint4*)sBw = *(const uint4*)(Bgs + kt);
    __syncthreads();
    #pragma unroll
    for (int i = 0; i < 2; i++){
      bf16x8 af = *(const bf16x8*)&sA[(wm * 32 + i * 16 + cl) * 32 + q * 8];
      #pragma unroll
      for (int j = 0; j < 2; j++){
        bf16x8 bfv = *(const bf16x8*)&sB[(wn * 32 + j * 16 + cl) * 32 + q * 8];
        acc[i][j] = __builtin_amdgcn_mfma_f32_16x16x32_bf16(af, bfv, acc[i][j], 0, 0, 0);
      }
    }
    __syncthreads();
  }
  #pragma unroll
  for (int i = 0; i < 2; i++)
    #pragma unroll
    for (int j = 0; j < 2; j++){
      int colg = tn * 64 + wn * 32 + j * 16 + cl;
      float bv = bias ? bias[colg] : 0.f;
      #pragma unroll
      for (int rr = 0; rr < 4; rr++){
        int rowg = tm * 64 + wm * 32 + i * 16 + q * 4 + rr;
        C[(long)rowg * ldc + colg] = acc[i][j][rr] + bv;
      }
    }
}

// ---------------- persistent LSTM: one launch, 64 ticks, grid barrier ----------------
// 64 WGs: 0..31 layer0 (cc=wg*16), 32..63 layer1. Weight slice (64 KB) pinned in LDS.
// LDS layout: fragment-contiguous, unit u=(kt*4+q)*4+g holds 16 rows (cl) x 8 elems.
__global__ __launch_bounds__(256, 1) void lstm_persist(
    const u16* whh0, const u16* wih1, const u16* whh1,
    const float* x0, const float* b1s,
    u16* h0b, u16* h1b, float* c0, float* c1,
    u16* feat, int* bar)
{
  __shared__ u16 sW[32768];   // 64 KB
  int wg = blockIdx.x;
  int layer = wg >> 5;
  int cc = (wg & 31) * 16;
  int tid = threadIdx.x;
  int wave = tid >> 6, lane = tid & 63;
  int q = lane >> 4, cl = lane & 15;

  // one-time weight stage: layer0 <- Whh0 slice, layer1 <- Wih1 slice
  {
    const u16* src = layer ? wih1 : whh0;
    for (int ch = tid; ch < 4096; ch += 256){
      int row = ch >> 6, c = ch & 63;     // row = g*16 + r (r = B-col), c = col-chunk (8 elems)
      int g = row >> 4, r = row & 15;
      *(uint4*)&sW[((c * 4 + g) * 16 + r) * 8] =
          *(const uint4*)&src[(long)(g * 512 + cc + r) * 512 + c * 8];
    }
  }
  __syncthreads();

  for (int k = 0; k < 64; k++){
    int t = layer ? (k - 1) : k;
    if (t >= 0 && t <= 62){
      const u16* h0p = h0b + ((k + 1) & 1) * (64 * 512);
      const u16* h1p = h1b + ((k + 1) & 1) * (64 * 512);
      f32x4 acc[4];
      #pragma unroll
      for (int g = 0; g < 4; g++) acc[g] = (f32x4){0.f, 0.f, 0.f, 0.f};

      // pass 0: A = h0(prev tick), B = LDS slice
      {
        const u16* Ab = h0p + (wave * 16 + cl) * 512 + q * 8;
        #pragma unroll 4
        for (int kt = 0; kt < 16; kt++){
          bf16x8 af = *(const bf16x8*)(Ab + kt * 32);
          #pragma unroll
          for (int g = 0; g < 4; g++){
            bf16x8 bfv = *(const bf16x8*)&sW[(((kt * 4 + q) * 4 + g) * 16 + cl) * 8];
            acc[g] = __builtin_amdgcn_mfma_f32_16x16x32_bf16(af, bfv, acc[g], 0, 0, 0);
          }
        }
      }
      // pass 1 (layer1 only): A = h1(prev tick), B = Whh1 slice from global (XCD-L2 resident)
      if (layer){
        const u16* Ab = h1p + (wave * 16 + cl) * 512 + q * 8;
        #pragma unroll 2
        for (int kt = 0; kt < 16; kt++){
          bf16x8 af = *(const bf16x8*)(Ab + kt * 32);
          #pragma unroll
          for (int g = 0; g < 4; g++){
            const u16* Bp = whh1 + (long)(g * 512 + cc + cl) * 512 + kt * 32 + q * 8;
            acc[g] = __builtin_amdgcn_mfma_f32_16x16x32_bf16(af, *(const bf16x8*)Bp, acc[g], 0, 0, 0);
          }
        }
      }
      // epilogue: gates -> c,h update
      u16* hn = (layer ? h1b : h0b) + (k & 1) * (64 * 512);
      float* cb = layer ? c1 : c0;
      #pragma unroll
      for (int rr = 0; rr < 4; rr++){
        int s = wave * 16 + q * 4 + rr;
        int j = cc + cl;
        float gi, gf, gg, go;
        if (layer == 0){
          const float* xr = x0 + (long)(t * 64 + s) * 2048 + j;
          gi = acc[0][rr] + xr[0];    gf = acc[1][rr] + xr[512];
          gg = acc[2][rr] + xr[1024]; go = acc[3][rr] + xr[1536];
        } else {
          gi = acc[0][rr] + b1s[j];        gf = acc[1][rr] + b1s[512 + j];
          gg = acc[2][rr] + b1s[1024 + j]; go = acc[3][rr] + b1s[1536 + j];
        }
        float cold = cb[s * 512 + j];
        float cn = sigmf(gf) * cold + sigmf(gi) * tanhf_(gg);
        cb[s * 512 + j] = cn;
        float hv = sigmf(go) * tanhf_(cn);
        u16 hb = f2bf(hv);
        hn[s * 512 + j] = hb;
        if (layer) feat[(long)(t * 64 + s) * 1024 + j] = hb;   // top_t
      }
    }
    // device-scope grid barrier (monotone counter; 64 WGs co-resident on 256 CUs)
    __syncthreads();
    if (tid == 0){
      __threadfence();
      __hip_atomic_fetch_add(bar, 1, __ATOMIC_ACQ_REL, __HIP_MEMORY_SCOPE_AGENT);
      int target = 64 * (k + 1);
      while (__hip_atomic_load(bar, __ATOMIC_ACQUIRE, __HIP_MEMORY_SCOPE_AGENT) < target)
        __builtin_amdgcn_s_sleep(1);
    }
    __syncthreads();
  }
}

// ---------------- attention scores: s[t,b,e] = sum_h vw[h]*tanh(q[t,b,h]+encp[b,e,h]) ----------------
__global__ __launch_bounds__(256) void k_scores(
    const float* qb, const float* encp, const float* vw, float* scores)
{
  int row = blockIdx.x;       // t*64 + b
  int b = row & 63;
  int wave = threadIdx.x >> 6, lane = threadIdx.x & 63;
  float qv[8], vwv[8];
  const float* qr = qb + (long)row * 512 + lane * 8;
  #pragma unroll
  for (int i = 0; i < 8; i++){ qv[i] = qr[i]; vwv[i] = vw[lane * 8 + i]; }
  for (int e = wave; e < 63; e += 4){
    const float* er = encp + (long)(b * 63 + e) * 512 + lane * 8;
    float s = 0.f;
    #pragma unroll
    for (int i = 0; i < 8; i++) s += vwv[i] * tanhf_(qv[i] + er[i]);
    s = wred64(s);
    if (lane == 0) scores[(long)row * 63 + e] = s;
  }
}

// ---------------- softmax over BATCH axis (reference quirk), in-place ----------------
__global__ __launch_bounds__(64) void k_att(float* scores, const unsigned char* mask){
  int idx = blockIdx.x;            // t*63 + e
  int t = idx / 63, e = idx - t * 63;
  int lane = threadIdx.x;          // = b
  long off = (long)(t * 64 + lane) * 63 + e;
  float s = scores[off];
  if (mask[((t + 62) % 63) * 63 + e]) s = NEGV;   // (t-1) mod 63
  float M = wmax64(s);
  float p = __expf(s - M);
  float S = wred64(p);
  scores[off] = p / S;
}

// ---------------- weighted[t,b,h] = sum_e att[t,b,e]*enc[b,e,h] -> feat[:,512:1024] ----------------
__global__ __launch_bounds__(256) void k_weighted(
    const float* att, const float* enc, u16* feat)
{
  int row = blockIdx.x;   // t*64 + b
  int b = row & 63;
  int j = threadIdx.x;
  float a0 = 0.f, a1 = 0.f;
  const float* ar = att + (long)row * 63;
  const float* er = enc + (long)b * 63 * 512;
  for (int e = 0; e < 63; e++){
    float a = ar[e];
    a0 += a * er[(long)e * 512 + j];
    a1 += a * er[(long)e * 512 + j + 256];
  }
  feat[(long)row * 1024 + 512 + j] = f2bf(a0);
  feat[(long)row * 1024 + 768 + j] = f2bf(a1);
}

// ---------------- fc GEMM 128x128 tiles + logsumexp-partial epilogue ----------------
// A = feat (4096,1024) bf16, B = fc_W (32000,1024) bf16. grid (32, 250).
__global__ __launch_bounds__(256) void gemm_fc(
    const u16* Am, const u16* Bm, const float* fcb, float* partials)
{
  __shared__ u16 sA[128 * 32], sB[128 * 32];
  __shared__ float sm[128][2], ss[128][2];
  int tm = blockIdx.x, tn = blockIdx.y;
  int tid = threadIdx.x;
  int wave = tid >> 6, lane = tid & 63;
  int wm = wave >> 1, wn = wave & 1;
  int q = lane >> 4, cl = lane & 15;
  f32x4 acc[4][4];
  #pragma unroll
  for (int i = 0; i < 4; i++)
    #pragma unroll
    for (int j = 0; j < 4; j++) acc[i][j] = (f32x4){0.f, 0.f, 0.f, 0.f};

  const u16 *Ag[2], *Bg[2];
  u16 *sAw[2], *sBw[2];
  #pragma unroll
  for (int h = 0; h < 2; h++){
    int idx = h * 256 + tid, rr = idx >> 2, ck = idx & 3;
    Ag[h] = Am + (long)(tm * 128 + rr) * 1024 + ck * 8;
    Bg[h] = Bm + (long)(tn * 128 + rr) * 1024 + ck * 8;
    sAw[h] = &sA[rr * 32 + ck * 8];
    sBw[h] = &sB[rr * 32 + ck * 8];
  }
  for (int kt = 0; kt < 1024; kt += 32){
    #pragma unroll
    for (int h = 0; h < 2; h++){
      *(uint4*)sAw[h] = *(const uint4*)(Ag[h] + kt);
      *(uint4*)sBw[h] = *(const uint4*)(Bg[h] + kt);
    }
    __syncthreads();
    bf16x8 afr[4];
    #pragma unroll
    for (int mt = 0; mt < 4; mt++)
      afr[mt] = *(const bf16x8*)&sA[(wm * 64 + mt * 16 + cl) * 32 + q * 8];
    #pragma unroll
    for (int nt = 0; nt < 4; nt++){
      bf16x8 bfv = *(const bf16x8*)&sB[(wn * 64 + nt * 16 + cl) * 32 + q * 8];
      #pragma unroll
      for (int mt = 0; mt < 4; mt++)
        acc[mt][nt] = __builtin_amdgcn_mfma_f32_16x16x32_bf16(afr[mt], bfv, acc[mt][nt], 0, 0, 0);
    }
    __syncthreads();
  }
  // per-row (max, sum-exp) over this WG's 128 cols
  float fb[4];
  #pragma unroll
  for (int nt = 0; nt < 4; nt++) fb[nt] = fcb[tn * 128 + wn * 64 + nt * 16 + cl];
  #pragma unroll
  for (int mt = 0; mt < 4; mt++){
    #pragma unroll
    for (int rr = 0; rr < 4; rr++){
      float vals[4];
      float vm = -3.0e38f, vs = 0.f;
      #pragma unroll
      for (int nt = 0; nt < 4; nt++){ float v = acc[mt][nt][rr] + fb[nt]; vals[nt] = v; vm = fmaxf(vm, v); }
      #pragma unroll
      for (int nt = 0; nt < 4; nt++) vs += __expf(vals[nt] - vm);
      #pragma unroll
      for (int m = 1; m < 16; m <<= 1){
        float om = __shfl_xor(vm, m, 16);
        float os = __shfl_xor(vs, m, 16);
        float nm = fmaxf(vm, om);
        vs = vs * __expf(vm - nm) + os * __expf(om - nm);
        vm = nm;
      }
      if (cl == 0){ int rl = wm * 64 + mt * 16 + q * 4 + rr; sm[rl][wn] = vm; ss[rl][wn] = vs; }
    }
  }
  __syncthreads();
  if (tid < 128){
    float m0 = sm[tid][0], m1 = sm[tid][1];
    float M = fmaxf(m0, m1);
    float S = ss[tid][0] * __expf(m0 - M) + ss[tid][1] * __expf(m1 - M);
    long row = tm * 128 + tid;
    partials[(row * 250 + tn) * 2]     = M;
    partials[(row * 250 + tn) * 2 + 1] = S;
  }
}

// ---------------- per-row logsumexp combine + target logit -> nll ----------------
__global__ __launch_bounds__(256) void k_rowstats(
    const float* partials, const u16* feat, const u16* fcwb,
    const float* fcb, const int* X, float* nll)
{
  int row = blockIdx.x * 4 + (threadIdx.x >> 6);
  int lane = threadIdx.x & 63;
  if (row >= 4032) return;
  float vm = -3.0e38f, vs = 0.f;
  const float* pr = partials + (long)row * 500;
  for (int i = lane; i < 250; i += 64){
    float m = pr[i * 2], s2 = pr[i * 2 + 1];
    float nm = fmaxf(vm, m);
    vs = vs * __expf(vm - nm) + s2 * __expf(m - nm);
    vm = nm;
  }
  #pragma unroll
  for (int m = 32; m; m >>= 1){
    float om = __shfl_xor(vm, m, 64);
    float os = __shfl_xor(vs, m, 64);
    float nm = fmaxf(vm, om);
    vs = vs * __expf(vm - nm) + os * __expf(om - nm);
    vm = nm;
  }
  float logZ = vm + __logf(vs);
  int t = row >> 6, b = row & 63;
  int tgt = X[b * 64 + t + 1];
  const u16* fr = feat + (long)row * 1024 + lane * 16;
  const u16* wr = fcwb + (long)tgt * 1024 + lane * 16;
  float d = 0.f;
  #pragma unroll
  for (int i = 0; i < 16; i++) d += bf2f(fr[i]) * bf2f(wr[i]);
  d = wred64(d);
  if (lane == 0) nll[row] = logZ - (d + fcb[tgt]);
}

// ---------------- final masked mean ----------------
__global__ __launch_bounds__(256) void k_final(const float* nll, const int* X, float* out){
  __shared__ float lt[64];
  int wave = threadIdx.x >> 6, lane = threadIdx.x & 63;
  for (int t = wave; t < 63; t += 4){
    int tgt = X[lane * 64 + t + 1];
    float v = (tgt != 0) ? nll[t * 64 + lane] : 0.f;
    float c = (tgt != 0) ? 1.f : 0.f;
    v = wred64(v); c = wred64(c);
    if (lane == 0) lt[t] = v / c;
  }
  __syncthreads();
  if (threadIdx.x == 0){
    float s = 0.f;
    for (int t = 0; t < 63; t++) s += lt[t];
    out[0] = s / 63.f;
  }
}

extern "C" void kernel_launch(void* const* d_in, const int* in_sizes, int n_in,
                              void* d_out, int out_size, void* d_ws, size_t ws_size,
                              hipStream_t stream)
{
  (void)in_sizes; (void)n_in; (void)out_size; (void)ws_size;
  const int*   X    = (const int*)d_in[0];
  const float* enc  = (const float*)d_in[1];
  const unsigned char* mask = (const unsigned char*)d_in[2];
  const float* emb  = (const float*)d_in[3];
  const float* wih  = (const float*)d_in[4];
  const float* whh  = (const float*)d_in[5];
  const float* bih  = (const float*)d_in[6];
  const float* bhh  = (const float*)d_in[7];
  const float* awh  = (const float*)d_in[8];
  const float* awe  = (const float*)d_in[9];
  const float* ab   = (const float*)d_in[10];
  const float* vw   = (const float*)d_in[11];
  const float* fcw  = (const float*)d_in[12];
  const float* fcb  = (const float*)d_in[13];
  float* out = (float*)d_out;

  char* w = (char*)d_ws;
  size_t o = 0;
  auto alloc = [&](size_t bytes){ size_t r = o; o = (o + bytes + 255) & ~(size_t)255; return r; };
  size_t o_ebf  = alloc((size_t)4032 * 512 * 2);
  size_t o_wihb = alloc((size_t)2 * 2048 * 512 * 2);
  size_t o_whhb = alloc((size_t)2 * 2048 * 512 * 2);
  size_t o_web  = alloc((size_t)512 * 512 * 2);
  size_t o_whb  = alloc((size_t)512 * 512 * 2);
  size_t o_fcwb = alloc((size_t)32000 * 1024 * 2);
  size_t o_encb = alloc((size_t)4032 * 512 * 2);
  size_t o_b01  = alloc((size_t)4096 * 4);
  size_t o_x0   = alloc((size_t)4032 * 2048 * 4);
  size_t o_encp = alloc((size_t)4032 * 512 * 4);
  size_t o_q    = alloc((size_t)4032 * 512 * 4);
  size_t o_feat = alloc((size_t)4096 * 1024 * 2);
  size_t o_hc   = alloc((size_t)(4 * 64 * 512 * 2 + 2 * 64 * 512 * 4));
  size_t o_bar  = alloc((size_t)256);
  size_t o_sc   = alloc((size_t)63 * 64 * 63 * 4);
  size_t o_part = alloc((size_t)4096 * 250 * 2 * 4);
  size_t o_nll  = alloc((size_t)4032 * 4);

  u16* ebf   = (u16*)(w + o_ebf);
  u16* wihb  = (u16*)(w + o_wihb);
  u16* whhb  = (u16*)(w + o_whhb);
  u16* web   = (u16*)(w + o_web);
  u16* whb   = (u16*)(w + o_whb);
  u16* fcwb  = (u16*)(w + o_fcwb);
  u16* encb  = (u16*)(w + o_encb);
  float* b01 = (float*)(w + o_b01);
  float* x0  = (float*)(w + o_x0);
  float* encp= (float*)(w + o_encp);
  float* qb  = (float*)(w + o_q);
  u16* feat  = (u16*)(w + o_feat);
  u16* h0b   = (u16*)(w + o_hc);
  u16* h1b   = h0b + 2 * 64 * 512;
  float* c0  = (float*)(h1b + 2 * 64 * 512);
  float* c1  = c0 + 64 * 512;
  int* bar   = (int*)(w + o_bar);
  float* sc  = (float*)(w + o_sc);
  float* part= (float*)(w + o_part);
  float* nllb= (float*)(w + o_nll);

  // zero h0[2], h1[2], c0, c1 + barrier counter (contiguous region)
  hipMemsetAsync(w + o_hc, 0, (o_bar - o_hc) + 256, stream);

  k_prep<<<4096, 256, 0, stream>>>(wih, whh, awe, awh, fcw, enc, bih, bhh,
                                   wihb, whhb, web, whb, fcwb, encb, b01);
  k_embed<<<4032, 256, 0, stream>>>(X, emb, ebf);

  // X0 = E @ Wih0^T + (bih0+bhh0): (4032,2048) K=512
  gemm_bt<<<dim3(63, 32), 256, 0, stream>>>(ebf, 512, wihb, 512, x0, 2048, b01, 512);
  // enc_proj = enc @ We^T + attn_b: (4032,512) K=512 (rows b*63+e)
  gemm_bt<<<dim3(63, 8), 256, 0, stream>>>(encb, 512, web, 512, encp, 512, ab, 512);

  // persistent LSTM: one launch, 64 internal ticks with device-scope grid barrier
  lstm_persist<<<64, 256, 0, stream>>>(whhb, wihb + 2048 * 512, whhb + 2048 * 512,
                                       x0, b01 + 2048, h0b, h1b, c0, c1, feat, bar);

  // q = top @ Wh^T: A = feat[:, :512] (lda=1024)
  gemm_bt<<<dim3(63, 8), 256, 0, stream>>>(feat, 1024, whb, 512, qb, 512, nullptr, 512);
  k_scores<<<4032, 256, 0, stream>>>(qb, encp, vw, sc);
  k_att<<<3969, 64, 0, stream>>>(sc, mask);
  k_weighted<<<4032, 256, 0, stream>>>(sc, enc, feat);

  gemm_fc<<<dim3(32, 250), 256, 0, stream>>>(feat, fcwb, fcb, part);
  k_rowstats<<<1008, 256, 0, stream>>>(part, feat, fcwb, fcb, X, nllb);
  k_final<<<1, 256, 0, stream>>>(nllb, X, out);
}

// Round 3
// 1869.021 us; speedup vs baseline: 1.2669x; 1.1790x over previous
//
#include <hip/hip_runtime.h>
#include <math.h>

// Problem constants: V=32000 D=512 H=512 L=2 B=64 S=64 -> T=Te=63
#define NEGV -1000000000.0f

typedef unsigned short u16;
typedef __attribute__((ext_vector_type(8))) short bf16x8;
typedef __attribute__((ext_vector_type(4))) float f32x4;

__device__ __forceinline__ u16 f2bf(float f){
  union { float f; unsigned u; } v; v.f = f;
  unsigned u = v.u;
  unsigned r = (u + 0x7fffu + ((u >> 16) & 1u)) >> 16;
  return (u16)r;
}
__device__ __forceinline__ float bf2f(u16 b){
  union { unsigned u; float f; } v; v.u = ((unsigned)b) << 16;
  return v.f;
}
__device__ __forceinline__ float sigmf(float x){ return 1.f / (1.f + __expf(-x)); }
__device__ __forceinline__ float tanhf_(float x){
  float e = __expf(-2.f * fabsf(x));
  float t = (1.f - e) / (1.f + e);
  return x >= 0.f ? t : -t;
}
__device__ __forceinline__ float wred64(float v){
  #pragma unroll
  for (int m = 32; m; m >>= 1) v += __shfl_xor(v, m, 64);
  return v;
}
__device__ __forceinline__ float wmax64(float v){
  #pragma unroll
  for (int m = 32; m; m >>= 1) v = fmaxf(v, __shfl_xor(v, m, 64));
  return v;
}

// ---------------- prep: fp32 -> bf16 weight copies + bias sums ----------------
__global__ __launch_bounds__(256) void k_prep(
    const float* wih, const float* whh, const float* we, const float* wh,
    const float* fcw, const float* enc, const float* bih, const float* bhh,
    u16* wihb, u16* whhb, u16* web, u16* whb, u16* fcwb, u16* encb, float* b01)
{
  const long n0 = 2097152, n1 = 2097152, n2 = 262144, n3 = 262144;
  const long n4 = 32768000, n5 = 2064384, n6 = 4096;
  const long total = n0 + n1 + n2 + n3 + n4 + n5 + n6;
  long stride = (long)gridDim.x * 256;
  for (long i = (long)blockIdx.x * 256 + threadIdx.x; i < total; i += stride){
    long j = i;
    if (j < n0){ wihb[j] = f2bf(wih[j]); continue; } j -= n0;
    if (j < n1){ whhb[j] = f2bf(whh[j]); continue; } j -= n1;
    if (j < n2){ web[j]  = f2bf(we[j]);  continue; } j -= n2;
    if (j < n3){ whb[j]  = f2bf(wh[j]);  continue; } j -= n3;
    if (j < n4){ fcwb[j] = f2bf(fcw[j]); continue; } j -= n4;
    if (j < n5){ encb[j] = f2bf(enc[j]); continue; } j -= n5;
    b01[j] = bih[j] + bhh[j];   // j<2048: layer0 bias sum; 2048..4095: layer1
  }
}

// ---------------- embedding gather -> bf16 ----------------
__global__ __launch_bounds__(256) void k_embed(const int* X, const float* emb, u16* ebf){
  int row = blockIdx.x;            // t*64 + b
  int t = row >> 6, b = row & 63;
  int tok = X[b * 64 + t];         // X is (B=64, S=64)
  const float* src = emb + (long)tok * 512;
  u16* dst = ebf + (long)row * 512;
  for (int j = threadIdx.x; j < 512; j += 256) dst[j] = f2bf(src[j]);
}

// ---------------- generic bf16 GEMM: C(M,N) = A(M,K) @ B(N,K)^T + bias (fp32 out) ----------------
__global__ __launch_bounds__(256) void gemm_bt(
    const u16* Am, int lda, const u16* Bm, int ldb,
    float* C, int ldc, const float* bias, int K)
{
  __shared__ u16 sA[64 * 32], sB[64 * 32];
  int tm = blockIdx.x, tn = blockIdx.y;
  int tid = threadIdx.x;
  int wave = tid >> 6, lane = tid & 63;
  int wm = wave >> 1, wn = wave & 1;
  int q = lane >> 4, cl = lane & 15;
  f32x4 acc[2][2];
  #pragma unroll
  for (int i = 0; i < 2; i++)
    #pragma unroll
    for (int j = 0; j < 2; j++) acc[i][j] = (f32x4){0.f, 0.f, 0.f, 0.f};

  int r = tid >> 2, ck = tid & 3;
  const u16* Ags = Am + (long)(tm * 64 + r) * lda + ck * 8;
  const u16* Bgs = Bm + (long)(tn * 64 + r) * ldb + ck * 8;
  u16* sAw = &sA[r * 32 + ck * 8];
  u16* sBw = &sB[r * 32 + ck * 8];

  for (int kt = 0; kt < K; kt += 32){
    *(uint4*)sAw = *(const uint4*)(Ags + kt);
    *(uint4*)sBw = *(const uint4*)(Bgs + kt);
    __syncthreads();
    #pragma unroll
    for (int i = 0; i < 2; i++){
      bf16x8 af = *(const bf16x8*)&sA[(wm * 32 + i * 16 + cl) * 32 + q * 8];
      #pragma unroll
      for (int j = 0; j < 2; j++){
        bf16x8 bfv = *(const bf16x8*)&sB[(wn * 32 + j * 16 + cl) * 32 + q * 8];
        acc[i][j] = __builtin_amdgcn_mfma_f32_16x16x32_bf16(af, bfv, acc[i][j], 0, 0, 0);
      }
    }
    __syncthreads();
  }
  #pragma unroll
  for (int i = 0; i < 2; i++)
    #pragma unroll
    for (int j = 0; j < 2; j++){
      int colg = tn * 64 + wn * 32 + j * 16 + cl;
      float bv = bias ? bias[colg] : 0.f;
      #pragma unroll
      for (int rr = 0; rr < 4; rr++){
        int rowg = tm * 64 + wm * 32 + i * 16 + q * 4 + rr;
        C[(long)rowg * ldc + colg] = acc[i][j][rr] + bv;
      }
    }
}

// ---------------- same GEMM but bf16 output (for x0 gate pre-activations) ----------------
__global__ __launch_bounds__(256) void gemm_btb(
    const u16* Am, int lda, const u16* Bm, int ldb,
    u16* C, int ldc, const float* bias, int K)
{
  __shared__ u16 sA[64 * 32], sB[64 * 32];
  int tm = blockIdx.x, tn = blockIdx.y;
  int tid = threadIdx.x;
  int wave = tid >> 6, lane = tid & 63;
  int wm = wave >> 1, wn = wave & 1;
  int q = lane >> 4, cl = lane & 15;
  f32x4 acc[2][2];
  #pragma unroll
  for (int i = 0; i < 2; i++)
    #pragma unroll
    for (int j = 0; j < 2; j++) acc[i][j] = (f32x4){0.f, 0.f, 0.f, 0.f};

  int r = tid >> 2, ck = tid & 3;
  const u16* Ags = Am + (long)(tm * 64 + r) * lda + ck * 8;
  const u16* Bgs = Bm + (long)(tn * 64 + r) * ldb + ck * 8;
  u16* sAw = &sA[r * 32 + ck * 8];
  u16* sBw = &sB[r * 32 + ck * 8];

  for (int kt = 0; kt < K; kt += 32){
    *(uint4*)sAw = *(const uint4*)(Ags + kt);
    *(uint4*)sBw = *(const uint4*)(Bgs + kt);
    __syncthreads();
    #pragma unroll
    for (int i = 0; i < 2; i++){
      bf16x8 af = *(const bf16x8*)&sA[(wm * 32 + i * 16 + cl) * 32 + q * 8];
      #pragma unroll
      for (int j = 0; j < 2; j++){
        bf16x8 bfv = *(const bf16x8*)&sB[(wn * 32 + j * 16 + cl) * 32 + q * 8];
        acc[i][j] = __builtin_amdgcn_mfma_f32_16x16x32_bf16(af, bfv, acc[i][j], 0, 0, 0);
      }
    }
    __syncthreads();
  }
  #pragma unroll
  for (int i = 0; i < 2; i++)
    #pragma unroll
    for (int j = 0; j < 2; j++){
      int colg = tn * 64 + wn * 32 + j * 16 + cl;
      float bv = bias ? bias[colg] : 0.f;
      #pragma unroll
      for (int rr = 0; rr < 4; rr++){
        int rowg = tm * 64 + wm * 32 + i * 16 + q * 4 + rr;
        C[(long)rowg * ldc + colg] = f2bf(acc[i][j][rr] + bv);
      }
    }
}

// ---------------- pipelined LSTM: per-WG progress flags, no global barrier ----------------
// flags[0..31] = layer0 WG tick counters, flags[32..63] = layer1.
// h rings: depth 4, ring[t&3]; ring[3] zero-init serves t=-1.
__device__ __forceinline__ void wait_flags(int* flags, int tid, int need0, int need1){
  if (tid < 64){
    for (;;){
      int v = __hip_atomic_load(flags + tid, __ATOMIC_ACQUIRE, __HIP_MEMORY_SCOPE_AGENT);
      int need = (tid < 32) ? need0 : need1;
      if (__ballot(v >= need) == ~0ull) break;
      __builtin_amdgcn_s_sleep(2);
    }
  }
  __syncthreads();
}

__global__ __launch_bounds__(256, 1) void lstm_pipe(
    const u16* whh0, const u16* wih1, const u16* whh1,
    const u16* x0b, const float* b1s,
    u16* ring0, u16* ring1, u16* feat, int* flags)
{
  __shared__ u16 sW[32768];   // 64 KB: layer0 <- Whh0 slice, layer1 <- Whh1 slice (critical-path B)
  int wg = blockIdx.x;
  int layer = wg >> 5;
  int cc = (wg & 31) * 16;
  int tid = threadIdx.x;
  int wave = tid >> 6, lane = tid & 63;
  int q = lane >> 4, cl = lane & 15;
  int j = cc + cl;

  // one-time weight stage (fragment-contiguous: unit (kt*4+q)*4+g holds 16 rows x 8 elems)
  {
    const u16* src = layer ? whh1 : whh0;
    for (int ch = tid; ch < 4096; ch += 256){
      int row = ch >> 6, c = ch & 63;
      int g = row >> 4, r = row & 15;
      *(uint4*)&sW[((c * 4 + g) * 16 + r) * 8] =
          *(const uint4*)&src[(long)(g * 512 + cc + r) * 512 + c * 8];
    }
  }
  __syncthreads();

  float cst[4] = {0.f, 0.f, 0.f, 0.f};   // register-resident c-state slice
  float bg[4];
  if (layer){
    #pragma unroll
    for (int g = 0; g < 4; g++) bg[g] = b1s[g * 512 + j];
  }

  const int LOW = -(1 << 30);

  for (int t = 0; t < 63; t++){
    f32x4 acc[4];
    #pragma unroll
    for (int g = 0; g < 4; g++) acc[g] = (f32x4){0.f, 0.f, 0.f, 0.f};

    if (layer == 0){
      // prefetch x0 gate slice (static data) BEFORE the wait
      float xg[4][4];
      #pragma unroll
      for (int rr = 0; rr < 4; rr++){
        int s = wave * 16 + q * 4 + rr;
        const u16* xr = x0b + (long)(t * 64 + s) * 2048 + j;
        #pragma unroll
        for (int g = 0; g < 4; g++) xg[g][rr] = bf2f(xr[g * 512]);
      }
      // need own group at t (h0(t-1) ready); back-pressure on layer1 readers of ring slot
      wait_flags(flags, tid, t, t - 3);
      const u16* h0p = ring0 + ((t + 3) & 3) * 32768;
      const u16* Ab = h0p + (wave * 16 + cl) * 512 + q * 8;
      #pragma unroll
      for (int kt = 0; kt < 16; kt++){
        bf16x8 af = *(const bf16x8*)(Ab + kt * 32);
        #pragma unroll
        for (int g = 0; g < 4; g++){
          bf16x8 bfv = *(const bf16x8*)&sW[(((kt * 4 + q) * 4 + g) * 16 + cl) * 8];
          acc[g] = __builtin_amdgcn_mfma_f32_16x16x32_bf16(af, bfv, acc[g], 0, 0, 0);
        }
      }
      u16* hn = ring0 + (t & 3) * 32768;
      #pragma unroll
      for (int rr = 0; rr < 4; rr++){
        int s = wave * 16 + q * 4 + rr;
        float gi = acc[0][rr] + xg[0][rr];
        float gf = acc[1][rr] + xg[1][rr];
        float gg = acc[2][rr] + xg[2][rr];
        float go = acc[3][rr] + xg[3][rr];
        float cn = sigmf(gf) * cst[rr] + sigmf(gi) * tanhf_(gg);
        cst[rr] = cn;
        hn[s * 512 + j] = f2bf(sigmf(go) * tanhf_(cn));
      }
    } else {
      // pass 0: input term h0(t) @ Wih1^T — wait only on layer0 progress
      wait_flags(flags, tid, t + 1, LOW);
      {
        const u16* h0c = ring0 + (t & 3) * 32768;
        const u16* Ab = h0c + (wave * 16 + cl) * 512 + q * 8;
        #pragma unroll
        for (int kt = 0; kt < 16; kt++){
          bf16x8 af = *(const bf16x8*)(Ab + kt * 32);
          #pragma unroll
          for (int g = 0; g < 4; g++){
            const u16* Bp = wih1 + (long)(g * 512 + cc + cl) * 512 + kt * 32 + q * 8;
            acc[g] = __builtin_amdgcn_mfma_f32_16x16x32_bf16(af, *(const bf16x8*)Bp, acc[g], 0, 0, 0);
          }
        }
      }
      // pass 1: recurrent term h1(t-1) @ Whh1^T — own-group wait (critical chain)
      wait_flags(flags, tid, LOW, t);
      {
        const u16* h1p = ring1 + ((t + 3) & 3) * 32768;
        const u16* Ab = h1p + (wave * 16 + cl) * 512 + q * 8;
        #pragma unroll
        for (int kt = 0; kt < 16; kt++){
          bf16x8 af = *(const bf16x8*)(Ab + kt * 32);
          #pragma unroll
          for (int g = 0; g < 4; g++){
            bf16x8 bfv = *(const bf16x8*)&sW[(((kt * 4 + q) * 4 + g) * 16 + cl) * 8];
            acc[g] = __builtin_amdgcn_mfma_f32_16x16x32_bf16(af, bfv, acc[g], 0, 0, 0);
          }
        }
      }
      u16* hn = ring1 + (t & 3) * 32768;
      #pragma unroll
      for (int rr = 0; rr < 4; rr++){
        int s = wave * 16 + q * 4 + rr;
        float gi = acc[0][rr] + bg[0];
        float gf = acc[1][rr] + bg[1];
        float gg = acc[2][rr] + bg[2];
        float go = acc[3][rr] + bg[3];
        float cn = sigmf(gf) * cst[rr] + sigmf(gi) * tanhf_(gg);
        cst[rr] = cn;
        u16 hb = f2bf(sigmf(go) * tanhf_(cn));
        hn[s * 512 + j] = hb;
        feat[(long)(t * 64 + s) * 1024 + j] = hb;   // top_t
      }
    }
    __syncthreads();   // drain all this WG's stores (s_waitcnt before s_barrier)
    if (tid == 0)
      __hip_atomic_store(flags + wg, t + 1, __ATOMIC_RELEASE, __HIP_MEMORY_SCOPE_AGENT);
  }
}

// ---------------- attention scores: s[t,b,e] = sum_h vw[h]*tanh(q[t,b,h]+encp[b,e,h]) ----------------
__global__ __launch_bounds__(256) void k_scores(
    const float* qb, const float* encp, const float* vw, float* scores)
{
  int row = blockIdx.x;       // t*64 + b
  int b = row & 63;
  int wave = threadIdx.x >> 6, lane = threadIdx.x & 63;
  float qv[8], vwv[8];
  const float* qr = qb + (long)row * 512 + lane * 8;
  #pragma unroll
  for (int i = 0; i < 8; i++){ qv[i] = qr[i]; vwv[i] = vw[lane * 8 + i]; }
  for (int e = wave; e < 63; e += 4){
    const float* er = encp + (long)(b * 63 + e) * 512 + lane * 8;
    float s = 0.f;
    #pragma unroll
    for (int i = 0; i < 8; i++) s += vwv[i] * tanhf_(qv[i] + er[i]);
    s = wred64(s);
    if (lane == 0) scores[(long)row * 63 + e] = s;
  }
}

// ---------------- softmax over BATCH axis (reference quirk), in-place ----------------
__global__ __launch_bounds__(64) void k_att(float* scores, const unsigned char* mask){
  int idx = blockIdx.x;            // t*63 + e
  int t = idx / 63, e = idx - t * 63;
  int lane = threadIdx.x;          // = b
  long off = (long)(t * 64 + lane) * 63 + e;
  float s = scores[off];
  if (mask[((t + 62) % 63) * 63 + e]) s = NEGV;   // (t-1) mod 63
  float M = wmax64(s);
  float p = __expf(s - M);
  float S = wred64(p);
  scores[off] = p / S;
}

// ---------------- weighted[t,b,h] = sum_e att[t,b,e]*enc[b,e,h] -> feat[:,512:1024] ----------------
__global__ __launch_bounds__(256) void k_weighted(
    const float* att, const float* enc, u16* feat)
{
  int row = blockIdx.x;   // t*64 + b
  int b = row & 63;
  int j = threadIdx.x;
  float a0 = 0.f, a1 = 0.f;
  const float* ar = att + (long)row * 63;
  const float* er = enc + (long)b * 63 * 512;
  for (int e = 0; e < 63; e++){
    float a = ar[e];
    a0 += a * er[(long)e * 512 + j];
    a1 += a * er[(long)e * 512 + j + 256];
  }
  feat[(long)row * 1024 + 512 + j] = f2bf(a0);
  feat[(long)row * 1024 + 768 + j] = f2bf(a1);
}

// ---------------- fc GEMM 128x128 tiles + logsumexp-partial epilogue ----------------
// A = feat (4096,1024) bf16, B = fc_W (32000,1024) bf16. grid (32, 250).
__global__ __launch_bounds__(256) void gemm_fc(
    const u16* Am, const u16* Bm, const float* fcb, float* partials)
{
  __shared__ u16 sA[128 * 32], sB[128 * 32];
  __shared__ float sm[128][2], ss[128][2];
  int tm = blockIdx.x, tn = blockIdx.y;
  int tid = threadIdx.x;
  int wave = tid >> 6, lane = tid & 63;
  int wm = wave >> 1, wn = wave & 1;
  int q = lane >> 4, cl = lane & 15;
  f32x4 acc[4][4];
  #pragma unroll
  for (int i = 0; i < 4; i++)
    #pragma unroll
    for (int j = 0; j < 4; j++) acc[i][j] = (f32x4){0.f, 0.f, 0.f, 0.f};

  const u16 *Ag[2], *Bg[2];
  u16 *sAw[2], *sBw[2];
  #pragma unroll
  for (int h = 0; h < 2; h++){
    int idx = h * 256 + tid, rr = idx >> 2, ck = idx & 3;
    Ag[h] = Am + (long)(tm * 128 + rr) * 1024 + ck * 8;
    Bg[h] = Bm + (long)(tn * 128 + rr) * 1024 + ck * 8;
    sAw[h] = &sA[rr * 32 + ck * 8];
    sBw[h] = &sB[rr * 32 + ck * 8];
  }
  for (int kt = 0; kt < 1024; kt += 32){
    #pragma unroll
    for (int h = 0; h < 2; h++){
      *(uint4*)sAw[h] = *(const uint4*)(Ag[h] + kt);
      *(uint4*)sBw[h] = *(const uint4*)(Bg[h] + kt);
    }
    __syncthreads();
    bf16x8 afr[4];
    #pragma unroll
    for (int mt = 0; mt < 4; mt++)
      afr[mt] = *(const bf16x8*)&sA[(wm * 64 + mt * 16 + cl) * 32 + q * 8];
    #pragma unroll
    for (int nt = 0; nt < 4; nt++){
      bf16x8 bfv = *(const bf16x8*)&sB[(wn * 64 + nt * 16 + cl) * 32 + q * 8];
      #pragma unroll
      for (int mt = 0; mt < 4; mt++)
        acc[mt][nt] = __builtin_amdgcn_mfma_f32_16x16x32_bf16(afr[mt], bfv, acc[mt][nt], 0, 0, 0);
    }
    __syncthreads();
  }
  float fb[4];
  #pragma unroll
  for (int nt = 0; nt < 4; nt++) fb[nt] = fcb[tn * 128 + wn * 64 + nt * 16 + cl];
  #pragma unroll
  for (int mt = 0; mt < 4; mt++){
    #pragma unroll
    for (int rr = 0; rr < 4; rr++){
      float vals[4];
      float vm = -3.0e38f, vs = 0.f;
      #pragma unroll
      for (int nt = 0; nt < 4; nt++){ float v = acc[mt][nt][rr] + fb[nt]; vals[nt] = v; vm = fmaxf(vm, v); }
      #pragma unroll
      for (int nt = 0; nt < 4; nt++) vs += __expf(vals[nt] - vm);
      #pragma unroll
      for (int m = 1; m < 16; m <<= 1){
        float om = __shfl_xor(vm, m, 16);
        float os = __shfl_xor(vs, m, 16);
        float nm = fmaxf(vm, om);
        vs = vs * __expf(vm - nm) + os * __expf(om - nm);
        vm = nm;
      }
      if (cl == 0){ int rl = wm * 64 + mt * 16 + q * 4 + rr; sm[rl][wn] = vm; ss[rl][wn] = vs; }
    }
  }
  __syncthreads();
  if (tid < 128){
    float m0 = sm[tid][0], m1 = sm[tid][1];
    float M = fmaxf(m0, m1);
    float S = ss[tid][0] * __expf(m0 - M) + ss[tid][1] * __expf(m1 - M);
    long row = tm * 128 + tid;
    partials[(row * 250 + tn) * 2]     = M;
    partials[(row * 250 + tn) * 2 + 1] = S;
  }
}

// ---------------- per-row logsumexp combine + target logit -> nll ----------------
__global__ __launch_bounds__(256) void k_rowstats(
    const float* partials, const u16* feat, const u16* fcwb,
    const float* fcb, const int* X, float* nll)
{
  int row = blockIdx.x * 4 + (threadIdx.x >> 6);
  int lane = threadIdx.x & 63;
  if (row >= 4032) return;
  float vm = -3.0e38f, vs = 0.f;
  const float* pr = partials + (long)row * 500;
  for (int i = lane; i < 250; i += 64){
    float m = pr[i * 2], s2 = pr[i * 2 + 1];
    float nm = fmaxf(vm, m);
    vs = vs * __expf(vm - nm) + s2 * __expf(m - nm);
    vm = nm;
  }
  #pragma unroll
  for (int m = 32; m; m >>= 1){
    float om = __shfl_xor(vm, m, 64);
    float os = __shfl_xor(vs, m, 64);
    float nm = fmaxf(vm, om);
    vs = vs * __expf(vm - nm) + os * __expf(om - nm);
    vm = nm;
  }
  float logZ = vm + __logf(vs);
  int t = row >> 6, b = row & 63;
  int tgt = X[b * 64 + t + 1];
  const u16* fr = feat + (long)row * 1024 + lane * 16;
  const u16* wr = fcwb + (long)tgt * 1024 + lane * 16;
  float d = 0.f;
  #pragma unroll
  for (int i = 0; i < 16; i++) d += bf2f(fr[i]) * bf2f(wr[i]);
  d = wred64(d);
  if (lane == 0) nll[row] = logZ - (d + fcb[tgt]);
}

// ---------------- final masked mean ----------------
__global__ __launch_bounds__(256) void k_final(const float* nll, const int* X, float* out){
  __shared__ float lt[64];
  int wave = threadIdx.x >> 6, lane = threadIdx.x & 63;
  for (int t = wave; t < 63; t += 4){
    int tgt = X[lane * 64 + t + 1];
    float v = (tgt != 0) ? nll[t * 64 + lane] : 0.f;
    float c = (tgt != 0) ? 1.f : 0.f;
    v = wred64(v); c = wred64(c);
    if (lane == 0) lt[t] = v / c;
  }
  __syncthreads();
  if (threadIdx.x == 0){
    float s = 0.f;
    for (int t = 0; t < 63; t++) s += lt[t];
    out[0] = s / 63.f;
  }
}

extern "C" void kernel_launch(void* const* d_in, const int* in_sizes, int n_in,
                              void* d_out, int out_size, void* d_ws, size_t ws_size,
                              hipStream_t stream)
{
  (void)in_sizes; (void)n_in; (void)out_size; (void)ws_size;
  const int*   X    = (const int*)d_in[0];
  const float* enc  = (const float*)d_in[1];
  const unsigned char* mask = (const unsigned char*)d_in[2];
  const float* emb  = (const float*)d_in[3];
  const float* wih  = (const float*)d_in[4];
  const float* whh  = (const float*)d_in[5];
  const float* bih  = (const float*)d_in[6];
  const float* bhh  = (const float*)d_in[7];
  const float* awh  = (const float*)d_in[8];
  const float* awe  = (const float*)d_in[9];
  const float* ab   = (const float*)d_in[10];
  const float* vw   = (const float*)d_in[11];
  const float* fcw  = (const float*)d_in[12];
  const float* fcb  = (const float*)d_in[13];
  float* out = (float*)d_out;

  char* w = (char*)d_ws;
  size_t o = 0;
  auto alloc = [&](size_t bytes){ size_t r = o; o = (o + bytes + 255) & ~(size_t)255; return r; };
  size_t o_ebf  = alloc((size_t)4032 * 512 * 2);
  size_t o_wihb = alloc((size_t)2 * 2048 * 512 * 2);
  size_t o_whhb = alloc((size_t)2 * 2048 * 512 * 2);
  size_t o_web  = alloc((size_t)512 * 512 * 2);
  size_t o_whb  = alloc((size_t)512 * 512 * 2);
  size_t o_fcwb = alloc((size_t)32000 * 1024 * 2);
  size_t o_encb = alloc((size_t)4032 * 512 * 2);
  size_t o_b01  = alloc((size_t)4096 * 4);
  size_t o_x0   = alloc((size_t)4032 * 2048 * 2);        // bf16 now
  size_t o_encp = alloc((size_t)4032 * 512 * 4);
  size_t o_q    = alloc((size_t)4032 * 512 * 4);
  size_t o_feat = alloc((size_t)4096 * 1024 * 2);
  size_t o_ring = alloc((size_t)2 * 4 * 32768 * 2);      // ring0 + ring1 (depth 4)
  size_t o_flags= alloc((size_t)256);
  size_t o_sc   = alloc((size_t)63 * 64 * 63 * 4);
  size_t o_part = alloc((size_t)4096 * 250 * 2 * 4);
  size_t o_nll  = alloc((size_t)4032 * 4);

  u16* ebf   = (u16*)(w + o_ebf);
  u16* wihb  = (u16*)(w + o_wihb);
  u16* whhb  = (u16*)(w + o_whhb);
  u16* web   = (u16*)(w + o_web);
  u16* whb   = (u16*)(w + o_whb);
  u16* fcwb  = (u16*)(w + o_fcwb);
  u16* encb  = (u16*)(w + o_encb);
  float* b01 = (float*)(w + o_b01);
  u16* x0b   = (u16*)(w + o_x0);
  float* encp= (float*)(w + o_encp);
  float* qb  = (float*)(w + o_q);
  u16* feat  = (u16*)(w + o_feat);
  u16* ring0 = (u16*)(w + o_ring);
  u16* ring1 = ring0 + 4 * 32768;
  int* flags = (int*)(w + o_flags);
  float* sc  = (float*)(w + o_sc);
  float* part= (float*)(w + o_part);
  float* nllb= (float*)(w + o_nll);

  // zero rings + flags (contiguous)
  hipMemsetAsync(w + o_ring, 0, (o_flags - o_ring) + 256, stream);

  k_prep<<<4096, 256, 0, stream>>>(wih, whh, awe, awh, fcw, enc, bih, bhh,
                                   wihb, whhb, web, whb, fcwb, encb, b01);
  k_embed<<<4032, 256, 0, stream>>>(X, emb, ebf);

  // X0 = E @ Wih0^T + (bih0+bhh0): (4032,2048) K=512, bf16 output
  gemm_btb<<<dim3(63, 32), 256, 0, stream>>>(ebf, 512, wihb, 512, x0b, 2048, b01, 512);
  // enc_proj = enc @ We^T + attn_b: (4032,512) K=512 (rows b*63+e)
  gemm_bt<<<dim3(63, 8), 256, 0, stream>>>(encb, 512, web, 512, encp, 512, ab, 512);

  // pipelined LSTM: one launch, per-WG flags, no global barrier
  lstm_pipe<<<64, 256, 0, stream>>>(whhb, wihb + 2048 * 512, whhb + 2048 * 512,
                                    x0b, b01 + 2048, ring0, ring1, feat, flags);

  // q = top @ Wh^T: A = feat[:, :512] (lda=1024)
  gemm_bt<<<dim3(63, 8), 256, 0, stream>>>(feat, 1024, whb, 512, qb, 512, nullptr, 512);
  k_scores<<<4032, 256, 0, stream>>>(qb, encp, vw, sc);
  k_att<<<3969, 64, 0, stream>>>(sc, mask);
  k_weighted<<<4032, 256, 0, stream>>>(sc, enc, feat);

  gemm_fc<<<dim3(32, 250), 256, 0, stream>>>(feat, fcwb, fcb, part);
  k_rowstats<<<1008, 256, 0, stream>>>(part, feat, fcwb, fcb, X, nllb);
  k_final<<<1, 256, 0, stream>>>(nllb, X, out);
}